// Round 1
// baseline (280.368 us; speedup 1.0000x reference)
//
#include <hip/hip_runtime.h>

#define BINS 10
#define WPB 4   // waves per block (256 threads)

// ws layout: float bce_sum[BINS]; int counts[BINS]
// (harness poisons ws to 0xAA before every launch -> must zero it ourselves)

__global__ __launch_bounds__(64) void ghmc_zero(float* ws_sum, int* ws_cnt) {
    int i = threadIdx.x;
    if (i < BINS) { ws_sum[i] = 0.0f; ws_cnt[i] = 0; }
}

__device__ __forceinline__ void ghmc_elem(float pk, float tk, float wk,
                                          float* wsum, int* wcnt) {
    if (wk > 0.0f) {
        // e = exp(-|p|) in (0,1];  1+e in (1,2] -> log well-conditioned
        float e    = __expf(-fabsf(pk));
        float onep = 1.0f + e;
        float r    = __builtin_amdgcn_rcpf(onep);      // sigmoid(|p|), ~1 ulp
        float s    = (pk >= 0.0f) ? r : (1.0f - r);    // sigmoid(p)
        float g    = fabsf(s - tk);                    // in [0,1]
        int bin = (int)(g * 10.0f);                    // floor (g>=0)
        bin = bin > (BINS - 1) ? (BINS - 1) : bin;
        // softplus(p) - p*t = max(p,0) + ln(1+e) - p*t ; ln(1+e) = ln2*log2(1+e)
        float bce = fmaxf(pk, 0.0f) - pk * tk + 0.69314718056f * __log2f(onep);
        // per-wave LDS histogram: ds_add_f32 / ds_add_u32, ~10-lane worst collision
        atomicAdd(&wsum[bin], bce);
        atomicAdd(&wcnt[bin], 1);
    }
}

__global__ __launch_bounds__(256) void ghmc_main(
    const float* __restrict__ pred, const float* __restrict__ targ,
    const float* __restrict__ lw,
    float* __restrict__ ws_sum, int* __restrict__ ws_cnt, int n) {

    // per-wave LDS bins: no cross-wave same-address serialization,
    // no 20-register accumulator array (the old version spilled: VGPR=28)
    __shared__ float s_sum[WPB][BINS];
    __shared__ int   s_cnt[WPB][BINS];
    if (threadIdx.x < WPB * BINS) {
        ((float*)s_sum)[threadIdx.x] = 0.0f;
        ((int*)s_cnt)[threadIdx.x]   = 0;
    }
    __syncthreads();

    const int wave = threadIdx.x >> 6;
    float* wsum = s_sum[wave];
    int*   wcnt = s_cnt[wave];

    const int tid    = blockIdx.x * blockDim.x + threadIdx.x;
    const int stride = gridDim.x * blockDim.x;
    const int nvec   = n >> 2;

    const float4* p4 = (const float4*)pred;
    const float4* t4 = (const float4*)targ;
    const float4* w4 = (const float4*)lw;

    for (int i = tid; i < nvec; i += stride) {
        float4 p = p4[i], t = t4[i], w = w4[i];
        const float* pp = (const float*)&p;
        const float* tt = (const float*)&t;
        const float* ww = (const float*)&w;
#pragma unroll
        for (int k = 0; k < 4; ++k)
            ghmc_elem(pp[k], tt[k], ww[k], wsum, wcnt);
    }
    // scalar tail (n not divisible by 4)
    {
        int rem = n & 3;
        if (tid < rem) {
            int i = (nvec << 2) + tid;
            ghmc_elem(pred[i], targ[i], lw[i], wsum, wcnt);
        }
    }

    __syncthreads();

    // block reduce: 10 lanes fold the 4 per-wave histograms, one global atomic each
    if (threadIdx.x < BINS) {
        float s = 0.0f;
        int   c = 0;
#pragma unroll
        for (int wv = 0; wv < WPB; ++wv) {
            s += s_sum[wv][threadIdx.x];
            c += s_cnt[wv][threadIdx.x];
        }
        if (c != 0) {
            atomicAdd(&ws_sum[threadIdx.x], s);
            atomicAdd(&ws_cnt[threadIdx.x], c);
        }
    }
}

__global__ __launch_bounds__(64) void ghmc_finalize(
    const float* __restrict__ ws_sum, const int* __restrict__ ws_cnt,
    float* __restrict__ out) {
    if (threadIdx.x == 0) {
        float acc = 0.0f;
        int n = 0;
        for (int b = 0; b < BINS; ++b) {
            int c = ws_cnt[b];
            if (c > 0) { n += 1; acc += ws_sum[b] / (float)c; }
        }
        out[0] = (n > 0) ? (acc / (float)n) : 0.0f;  // LOSS_WEIGHT = 1
    }
}

extern "C" void kernel_launch(void* const* d_in, const int* in_sizes, int n_in,
                              void* d_out, int out_size, void* d_ws, size_t ws_size,
                              hipStream_t stream) {
    const float* pred = (const float*)d_in[0];
    const float* targ = (const float*)d_in[1];
    const float* lw   = (const float*)d_in[2];
    float* out = (float*)d_out;
    const int n = in_sizes[0];   // 262144*80 = 20,971,520

    float* ws_sum = (float*)d_ws;
    int*   ws_cnt = (int*)((char*)d_ws + BINS * sizeof(float));

    ghmc_zero<<<1, 64, 0, stream>>>(ws_sum, ws_cnt);

    const int threads = 256;
    const int blocks  = 2048;   // 8 blocks/CU on 256 CUs, grid-stride
    ghmc_main<<<blocks, threads, 0, stream>>>(pred, targ, lw, ws_sum, ws_cnt, n);

    ghmc_finalize<<<1, 64, 0, stream>>>(ws_sum, ws_cnt, out);
}

// Round 2
// 261.809 us; speedup vs baseline: 1.0709x; 1.0709x over previous
//
#include <hip/hip_runtime.h>

#define BINS 10

// ws layout: float bce_sum[BINS]; int counts[BINS]
// (harness poisons ws to 0xAA before every launch -> must zero it ourselves)

__global__ __launch_bounds__(64) void ghmc_zero(float* ws_sum, int* ws_cnt) {
    int i = threadIdx.x;
    if (i < BINS) { ws_sum[i] = 0.0f; ws_cnt[i] = 0; }
}

// Per-element update, expanded INLINE in the kernel body (macro, not a function:
// round-0 passed the accumulator arrays as pointer args, which blocked SROA and
// spilled the 20-entry histogram to scratch -> 350 instr/element).
// After unroll every lsum[b]/lcnt[b] index is a constant -> stays in VGPRs.
#define GHMC_ELEM(pk, tk, wk)                                               \
    do {                                                                    \
        float e_   = __expf(-fabsf(pk));           /* exp(-|p|) in (0,1] */ \
        float onep = 1.0f + e_;                    /* (1,2]: log is exact*/ \
        float r_   = __builtin_amdgcn_rcpf(onep);  /* sigmoid(|p|)       */ \
        float s_   = (pk >= 0.0f) ? r_ : (1.0f - r_);                       \
        float g_   = fabsf(s_ - tk);               /* in [0,1]           */ \
        int bin_   = (int)(g_ * 10.0f);            /* floor, g>=0        */ \
        bin_       = bin_ > (BINS - 1) ? (BINS - 1) : bin_;                 \
        bin_       = (wk > 0.0f) ? bin_ : -1;      /* invalid -> no bin  */ \
        float bce_ = fmaxf(pk, 0.0f) - pk * tk                              \
                     + 0.69314718055994530942f * __log2f(onep);             \
        _Pragma("unroll")                                                   \
        for (int b = 0; b < BINS; ++b) {                                    \
            bool m_ = (bin_ == b);                                          \
            lsum[b] += m_ ? bce_ : 0.0f;                                    \
            lcnt[b] += m_ ? 1 : 0;                                          \
        }                                                                   \
    } while (0)

__global__ __launch_bounds__(256) void ghmc_main(
    const float* __restrict__ pred, const float* __restrict__ targ,
    const float* __restrict__ lw,
    float* __restrict__ ws_sum, int* __restrict__ ws_cnt, int n) {

    // per-lane register histogram: zero LDS traffic in the hot loop
    float lsum[BINS];
    int   lcnt[BINS];
#pragma unroll
    for (int b = 0; b < BINS; ++b) { lsum[b] = 0.0f; lcnt[b] = 0; }

    const int tid    = blockIdx.x * blockDim.x + threadIdx.x;
    const int stride = gridDim.x * blockDim.x;
    const int nvec   = n >> 2;

    const float4* p4 = (const float4*)pred;
    const float4* t4 = (const float4*)targ;
    const float4* w4 = (const float4*)lw;

    // manual 1-deep prefetch: next iteration's 3 loads are in flight while
    // the current 4 elements are processed (VGPRs now allow it)
    int i = tid;
    if (i < nvec) {
        float4 p = p4[i], t = t4[i], w = w4[i];
        for (int j = i + stride; j < nvec; j += stride) {
            float4 pn = p4[j], tn = t4[j], wn = w4[j];
            GHMC_ELEM(p.x, t.x, w.x);
            GHMC_ELEM(p.y, t.y, w.y);
            GHMC_ELEM(p.z, t.z, w.z);
            GHMC_ELEM(p.w, t.w, w.w);
            p = pn; t = tn; w = wn;
        }
        GHMC_ELEM(p.x, t.x, w.x);
        GHMC_ELEM(p.y, t.y, w.y);
        GHMC_ELEM(p.z, t.z, w.z);
        GHMC_ELEM(p.w, t.w, w.w);
    }
    // scalar tail (n not divisible by 4)
    {
        int rem = n & 3;
        if (tid < rem) {
            int idx = (nvec << 2) + tid;
            float pk = pred[idx], tk = targ[idx], wk = lw[idx];
            GHMC_ELEM(pk, tk, wk);
        }
    }

    // ---- wave (64-lane) butterfly reduction per bin, once per kernel ----
    __shared__ float s_sum[BINS];
    __shared__ int   s_cnt[BINS];
    if (threadIdx.x < BINS) { s_sum[threadIdx.x] = 0.0f; s_cnt[threadIdx.x] = 0; }
    __syncthreads();

    const int lane = threadIdx.x & 63;
#pragma unroll
    for (int b = 0; b < BINS; ++b) {
        float s = lsum[b];
        int   c = lcnt[b];
#pragma unroll
        for (int off = 32; off > 0; off >>= 1) {
            s += __shfl_xor(s, off, 64);
            c += __shfl_xor(c, off, 64);
        }
        if (lane == 0 && c != 0) {
            atomicAdd(&s_sum[b], s);   // 4 waves/block -> <=40 LDS atomics total
            atomicAdd(&s_cnt[b], c);
        }
    }
    __syncthreads();

    if (threadIdx.x < BINS) {
        float s = s_sum[threadIdx.x];
        int   c = s_cnt[threadIdx.x];
        if (c != 0) {
            atomicAdd(&ws_sum[threadIdx.x], s);
            atomicAdd(&ws_cnt[threadIdx.x], c);
        }
    }
}

__global__ __launch_bounds__(64) void ghmc_finalize(
    const float* __restrict__ ws_sum, const int* __restrict__ ws_cnt,
    float* __restrict__ out) {
    if (threadIdx.x == 0) {
        float acc = 0.0f;
        int nb = 0;
        for (int b = 0; b < BINS; ++b) {
            int c = ws_cnt[b];
            if (c > 0) { nb += 1; acc += ws_sum[b] / (float)c; }
        }
        out[0] = (nb > 0) ? (acc / (float)nb) : 0.0f;  // LOSS_WEIGHT = 1
    }
}

extern "C" void kernel_launch(void* const* d_in, const int* in_sizes, int n_in,
                              void* d_out, int out_size, void* d_ws, size_t ws_size,
                              hipStream_t stream) {
    const float* pred = (const float*)d_in[0];
    const float* targ = (const float*)d_in[1];
    const float* lw   = (const float*)d_in[2];
    float* out = (float*)d_out;
    const int n = in_sizes[0];   // 262144*80 = 20,971,520

    float* ws_sum = (float*)d_ws;
    int*   ws_cnt = (int*)((char*)d_ws + BINS * sizeof(float));

    ghmc_zero<<<1, 64, 0, stream>>>(ws_sum, ws_cnt);

    const int threads = 256;
    const int blocks  = 2048;   // 8 blocks/CU on 256 CUs, grid-stride
    ghmc_main<<<blocks, threads, 0, stream>>>(pred, targ, lw, ws_sum, ws_cnt, n);

    ghmc_finalize<<<1, 64, 0, stream>>>(ws_sum, ws_cnt, out);
}